// Round 7
// baseline (840.591 us; speedup 1.0000x reference)
//
#include <hip/hip_runtime.h>

#define TOKENS 18
#define QLEN 9
#define HDIM 1024
#define IDIM 4096
#define NLAYER 8

// ws layout (float offsets)
#define HA_OFF    0u          // h (layer input / final): [18][1024]
#define HB_OFF    18432u      // h after attn residual:   [18][1024]
#define SQP_OFF   36864u      // sumsq partials [18][8]
#define RSTD_OFF  37008u      // rstd1 slots [8 layers][18]
#define CNT_OFF   37152u      // 64 u32 flags (per-layer cnt)
#define QKVR_OFF  37248u      // reduced qkv [18][1280]
#define QKVP_OFF  60288u      // qkv partials [32][18][1280]
#define OPP_OFF   797568u     // attn-out partials [32][18][1024]
#define GUP_OFF   1387392u    // gu partials [64][18][8192]
#define WDP_OFF   10824576u   // wd partials [256][18][1024]
#define OUTP_OFF  15543168u   // out partials [32][512]
#define TOTAL_F   15559552u   // ~62 MB

// ---------------- reg-dbuf GEMV helpers ---------------------------------------------
__device__ __forceinline__ void load8(float4* buf, const float* wp, int cc, int stride) {
#pragma unroll
  for (int j = 0; j < 8; j++)
    buf[j] = *reinterpret_cast<const float4*>(wp + (size_t)(cc * 8 + j) * stride);
}
__device__ __forceinline__ void fma8(float4* acc, const float4* buf,
                                     const float (*sb)[TOKENS], int cc) {
#pragma unroll
  for (int j = 0; j < 8; j++) {
#pragma unroll
    for (int t = 0; t < TOKENS; t++) {
      float bv = sb[cc * 8 + j][t];
      acc[t].x += bv * buf[j].x; acc[t].y += bv * buf[j].y;
      acc[t].z += bv * buf[j].z; acc[t].w += bv * buf[j].w;
    }
  }
}
__device__ __forceinline__ void loadf2(float2* buf, const float* wp, int base, int stride) {
#pragma unroll
  for (int j = 0; j < 8; j++)
    buf[j] = *reinterpret_cast<const float2*>(wp + (size_t)(base + j) * stride);
}
__device__ __forceinline__ void fmaf2(float2* acc, const float2* buf,
                                      const float (*sb)[TOKENS], int base) {
#pragma unroll
  for (int j = 0; j < 8; j++) {
#pragma unroll
    for (int t = 0; t < TOKENS; t++) {
      float bv = sb[base + j][t];
      acc[t].x += bv * buf[j].x; acc[t].y += bv * buf[j].y;
    }
  }
}
__device__ __forceinline__ void loadf1(float* buf, const float* wp, int base, int stride) {
#pragma unroll
  for (int j = 0; j < 8; j++) buf[j] = wp[(size_t)(base + j) * stride];
}
__device__ __forceinline__ void fmaf1(float* acc, const float* buf,
                                      const float (*sb)[TOKENS], int base) {
#pragma unroll
  for (int j = 0; j < 8; j++) {
#pragma unroll
    for (int t = 0; t < TOKENS; t++) acc[t] += sb[base + j][t] * buf[j];
  }
}

// ---------------- K0: build h_a + sumsq partials (144 = 18 tok x 8 chunks) ----------
__global__ __launch_bounds__(256) void k_embed(
    const float* __restrict__ rnd, const float* __restrict__ dit,
    const float* __restrict__ feat, const float* __restrict__ t_all,
    const float* __restrict__ W_in, const float* __restrict__ b_in,
    const int* __restrict__ step, float* __restrict__ ws) {
  int t = blockIdx.x >> 3, ch = blockIdx.x & 7, c0 = ch * 128;
  int b = t / QLEN, q = t - b * QLEN;
  int tid = threadIdx.x;
  __shared__ float hv[128];
  __shared__ float red[2][128];
  __shared__ float pr[2];
  int st = step[0];
  if (q < 5) {
    if (tid < 128) {
      int c = c0 + tid;
      float v;
      if (q == 0) v = t_all[(size_t)st * HDIM + c] + (b == 0 ? dit[c] : 0.f);
      else        v = feat[(size_t)(b * 4 + q - 1) * HDIM + c];
      hv[tid] = v;
    }
  } else {
    int p = q - 5;
    int el = tid & 127, hf = tid >> 7;
    float a = 0.f;
#pragma unroll
    for (int f = 0; f < 32; f++) a += rnd[p * 64 + hf * 32 + f] * W_in[(size_t)(hf * 32 + f) * HDIM + c0 + el];
    red[hf][el] = a;
    __syncthreads();
    if (tid < 128) hv[tid] = red[0][tid] + red[1][tid] + b_in[c0 + tid];
  }
  __syncthreads();
  if (tid < 128) ws[HA_OFF + (size_t)t * HDIM + c0 + tid] = hv[tid];
  if (tid < 64) {
    float s = hv[tid] * hv[tid] + hv[tid + 64] * hv[tid + 64];
#pragma unroll
    for (int off = 32; off >= 1; off >>= 1) s += __shfl_down(s, off);
    if (tid == 0) pr[0] = s;
  }
  __syncthreads();
  if (tid == 0) ws[SQP_OFF + (size_t)t * 8 + ch] = pr[0];
}

// ---------------- K1: qkv partials = rms(h_a)*ln1 @ [Wq|Wk|Wv] (3,32) ---------------
__global__ __launch_bounds__(256) void k_qkv(
    const float* __restrict__ Wq, const float* __restrict__ Wk,
    const float* __restrict__ Wv, const float* __restrict__ ln1,
    float* __restrict__ ws, int layer) {
  int ks = blockIdx.y, r0 = ks * 32, bx = blockIdx.x, tid = threadIdx.x;
  __shared__ float s_b[32][TOKENS];
  __shared__ float s_rstd[TOKENS];
  if (tid < TOKENS) {
    float s = 0.f;
#pragma unroll
    for (int ch = 0; ch < 8; ch++) s += ws[SQP_OFF + (size_t)tid * 8 + ch];
    s_rstd[tid] = rsqrtf(s * (1.f / HDIM) + 1e-6f);
  }
  const float* lw = ln1 + (size_t)layer * HDIM;
  for (int i = tid; i < 576; i += 256) {
    int t = i >> 5, r = i & 31;
    s_b[r][t] = ws[HA_OFF + (size_t)t * HDIM + r0 + r] * lw[r0 + r];
  }
  __syncthreads();
  float* qp = ws + QKVP_OFF + (size_t)ks * (TOKENS * 1280);
  if (bx < 2) {
    int col = bx * 512 + tid * 2;
    const float* wp = Wq + ((size_t)layer << 20) + (size_t)r0 * HDIM + col;
    float2 A[8], B[8];
    float2 acc[TOKENS];
#pragma unroll
    for (int t = 0; t < TOKENS; t++) acc[t] = make_float2(0.f, 0.f);
    loadf2(A, wp, 0, HDIM); loadf2(B, wp, 8, HDIM);
    fmaf2(acc, A, s_b, 0);  loadf2(A, wp, 16, HDIM);
    fmaf2(acc, B, s_b, 8);  loadf2(B, wp, 24, HDIM);
    fmaf2(acc, A, s_b, 16); fmaf2(acc, B, s_b, 24);
#pragma unroll
    for (int t = 0; t < TOKENS; t++) {
      float rs = s_rstd[t];
      *reinterpret_cast<float2*>(qp + (size_t)t * 1280 + col) = make_float2(acc[t].x * rs, acc[t].y * rs);
    }
  } else {
    int c = tid;   // 0..255 -> k cols 0..127, v cols 0..127
    const float* wp = (c < 128)
      ? (Wk + (size_t)layer * 131072 + (size_t)r0 * 128 + c)
      : (Wv + (size_t)layer * 131072 + (size_t)r0 * 128 + (c - 128));
    float A[8], B[8];
    float acc[TOKENS];
#pragma unroll
    for (int t = 0; t < TOKENS; t++) acc[t] = 0.f;
    loadf1(A, wp, 0, 128); loadf1(B, wp, 8, 128);
    fmaf1(acc, A, s_b, 0);  loadf1(A, wp, 16, 128);
    fmaf1(acc, B, s_b, 8);  loadf1(B, wp, 24, 128);
    fmaf1(acc, A, s_b, 16); fmaf1(acc, B, s_b, 24);
#pragma unroll
    for (int t = 0; t < TOKENS; t++) qp[(size_t)t * 1280 + 1024 + c] = acc[t] * s_rstd[t];
  }
}

// ---------------- K2: reduce qkv partials (90 blocks, exact) ------------------------
__global__ __launch_bounds__(256) void k_redq(float* __restrict__ ws) {
  int el = blockIdx.x * 256 + threadIdx.x;   // 23040 exactly
  float s = 0.f;
#pragma unroll 8
  for (int p = 0; p < 32; p++) s += ws[QKVP_OFF + (size_t)p * (TOKENS * 1280) + el];
  ws[QKVR_OFF + el] = s;
}

// ---------------- K3: attn (from reduced qkv) + Wo partials (2,32) ------------------
__global__ __launch_bounds__(256) void k_wo(
    const float* __restrict__ Wo, const float* __restrict__ cosq,
    const float* __restrict__ sinq, float* __restrict__ ws, int layer) {
  const float* qkv = ws + QKVR_OFF;
  int bx = blockIdx.x, by = blockIdx.y, tid = threadIdx.x;
  int r0 = by * 32, head = r0 >> 6, kvh = head >> 3, d0 = r0 & 63;
  __shared__ float lq[2][QLEN][68];
  __shared__ float lk[2][QLEN][68];
  __shared__ float lv[2][QLEN][33];
  __shared__ float sP[2][QLEN][12];
  __shared__ float sA[32][TOKENS];
  for (int i = tid; i < 2 * QLEN * 64; i += 256) {
    int d = i & 63, qi = (i >> 6) % QLEN, b = i / (QLEN * 64);
    const float* qr = qkv + (size_t)(b * QLEN + qi) * 1280;
    float c = cosq[qi * 64 + d], s = sinq[qi * 64 + d];
    float qv = qr[head * 64 + d];
    float qo = (d < 32) ? -qr[head * 64 + d + 32] : qr[head * 64 + d - 32];
    lq[b][qi][d] = qv * c + qo * s;
    float kv = qr[1024 + kvh * 64 + d];
    float ko = (d < 32) ? -qr[1024 + kvh * 64 + d + 32] : qr[1024 + kvh * 64 + d - 32];
    lk[b][qi][d] = kv * c + ko * s;
  }
  for (int i = tid; i < 2 * QLEN * 32; i += 256) {
    int d = i & 31, ki = (i >> 5) % QLEN, b = i / (QLEN * 32);
    lv[b][ki][d] = qkv[(size_t)(b * QLEN + ki) * 1280 + 1152 + kvh * 64 + d0 + d];
  }
  __syncthreads();
  for (int i = tid; i < 2 * QLEN * QLEN; i += 256) {
    int ki = i % QLEN, qi = (i / QLEN) % QLEN, b = i / (QLEN * QLEN);
    float s = 0.f;
#pragma unroll
    for (int d = 0; d < 64; d++) s += lq[b][qi][d] * lk[b][ki][d];
    sP[b][qi][ki] = s;
  }
  __syncthreads();
  if (tid < TOKENS) {
    int b = tid / QLEN, qi = tid % QLEN;
    float m = -1e30f;
#pragma unroll
    for (int k = 0; k < QLEN; k++) m = fmaxf(m, sP[b][qi][k]);
    float e[QLEN], sum = 0.f;
#pragma unroll
    for (int k = 0; k < QLEN; k++) { e[k] = expf(sP[b][qi][k] - m); sum += e[k]; }
    float inv = 1.f / sum;
#pragma unroll
    for (int k = 0; k < QLEN; k++) sP[b][qi][k] = e[k] * inv;
  }
  __syncthreads();
  for (int i = tid; i < 32 * TOKENS; i += 256) {
    int dd = i / TOKENS, t = i - dd * TOKENS;
    int b = t / QLEN, qi = t % QLEN;
    float a = 0.f;
#pragma unroll
    for (int k = 0; k < QLEN; k++) a += sP[b][qi][k] * lv[b][k][dd];
    sA[dd][t] = a;
  }
  __syncthreads();
  int col = bx * 512 + tid * 2;
  const float* wp = Wo + ((size_t)layer << 20) + (size_t)r0 * HDIM + col;
  float2 A[8], B[8];
  float2 acc[TOKENS];
#pragma unroll
  for (int t = 0; t < TOKENS; t++) acc[t] = make_float2(0.f, 0.f);
  loadf2(A, wp, 0, HDIM); loadf2(B, wp, 8, HDIM);
  fmaf2(acc, A, sA, 0);   loadf2(A, wp, 16, HDIM);
  fmaf2(acc, B, sA, 8);   loadf2(B, wp, 24, HDIM);
  fmaf2(acc, A, sA, 16);  fmaf2(acc, B, sA, 24);
  float* op = ws + OPP_OFF + (size_t)by * (TOKENS * HDIM);
#pragma unroll
  for (int t = 0; t < TOKENS; t++)
    *reinterpret_cast<float2*>(op + (size_t)t * HDIM + col) = acc[t];
}

// ---------------- K4: gu partials; 18 producer blocks emit h_b + rstd ---------------
__global__ __launch_bounds__(256) void k_gu(
    const float* __restrict__ Wg, const float* __restrict__ Wu,
    const float* __restrict__ ln2, float* __restrict__ ws, int layer) {
  int cg = blockIdx.x, ksx = blockIdx.y, r0 = ksx * 16, tid = threadIdx.x;
  unsigned* cnt = (unsigned*)(ws + CNT_OFF) + layer;
  float* rstd_ws = ws + RSTD_OFF + (size_t)layer * TOKENS;
  __shared__ float s_b[16][TOKENS];
  __shared__ float s_rstd[TOKENS];
  __shared__ float pr[4];
  // producer: full-token h1 = h_a + sum(op) -> h_b, rstd
  if (cg == 0 && ksx < TOKENS) {
    int t = ksx, c4 = tid * 4;
    float4 s = *reinterpret_cast<const float4*>(ws + HA_OFF + (size_t)t * HDIM + c4);
    const float* opp = ws + OPP_OFF + (size_t)t * HDIM + c4;
#pragma unroll 8
    for (int p = 0; p < 32; p++) {
      float4 o = *reinterpret_cast<const float4*>(opp + (size_t)p * (TOKENS * HDIM));
      s.x += o.x; s.y += o.y; s.z += o.z; s.w += o.w;
    }
    *reinterpret_cast<float4*>(ws + HB_OFF + (size_t)t * HDIM + c4) = s;
    float sq = s.x * s.x + s.y * s.y + s.z * s.z + s.w * s.w;
#pragma unroll
    for (int off = 32; off >= 1; off >>= 1) sq += __shfl_down(sq, off);
    if ((tid & 63) == 0) pr[tid >> 6] = sq;
    __syncthreads();
    if (tid == 0) {
      float tot = pr[0] + pr[1] + pr[2] + pr[3];
      rstd_ws[t] = rsqrtf(tot * (1.f / HDIM) + 1e-6f);
      __threadfence();
      __hip_atomic_fetch_add(cnt, 1u, __ATOMIC_RELEASE, __HIP_MEMORY_SCOPE_AGENT);
    }
  }
  // consumer: slice h1 update (independent of producers)
  const float* lw = ln2 + (size_t)layer * HDIM;
  for (int i = tid; i < 288; i += 256) {
    int t = i >> 4, r = i & 15;
    const float* pp = ws + OPP_OFF + (size_t)t * HDIM + r0 + r;
    float v = ws[HA_OFF + (size_t)t * HDIM + r0 + r];
#pragma unroll 8
    for (int p = 0; p < 32; p++) v += pp[(size_t)p * (TOKENS * HDIM)];
    s_b[r][t] = v * lw[r0 + r];
  }
  __syncthreads();
  const float* W = (cg < 4 ? Wg : Wu) + ((size_t)layer << 22);
  int c = (cg & 3) * 1024 + tid * 4;
  const float* wp = W + (size_t)r0 * IDIM + c;
  float4 A[8], B[8];
  float4 acc[TOKENS];
#pragma unroll
  for (int t = 0; t < TOKENS; t++) acc[t] = make_float4(0.f, 0.f, 0.f, 0.f);
  load8(A, wp, 0, IDIM);
  load8(B, wp, 1, IDIM);
  fma8(acc, A, s_b, 0);
  fma8(acc, B, s_b, 1);
  // wait for rstd (producers finished long ago)
  if (tid == 0) {
    while (__hip_atomic_load(cnt, __ATOMIC_ACQUIRE, __HIP_MEMORY_SCOPE_AGENT) < (unsigned)TOKENS)
      __builtin_amdgcn_s_sleep(2);
  }
  __syncthreads();
  if (tid < TOKENS) s_rstd[tid] = rstd_ws[tid];
  __syncthreads();
  float* gp = ws + GUP_OFF + (size_t)ksx * (TOKENS * 8192) + cg * 1024 + tid * 4;
#pragma unroll
  for (int t = 0; t < TOKENS; t++) {
    float rs = s_rstd[t];
    *reinterpret_cast<float4*>(gp + (size_t)t * 8192) =
      make_float4(acc[t].x * rs, acc[t].y * rs, acc[t].z * rs, acc[t].w * rs);
  }
}

// ---------------- K5: wd partials = silu(g)*u @ Wd (256 blocks, 16 rows) ------------
__global__ __launch_bounds__(256) void k_wd(
    const float* __restrict__ Wd, float* __restrict__ ws, int layer) {
  int bid = blockIdx.x, tid = threadIdx.x;
  int r0 = bid * 16;
  __shared__ float s_b[16][TOKENS];
  for (int i = tid; i < 288; i += 256) {
    int t = i >> 4, r = i & 15;
    const float* gp = ws + GUP_OFF + (size_t)t * 8192 + r0 + r;
    float g = 0.f, u = 0.f;
#pragma unroll 8
    for (int p = 0; p < 64; p++) {
      g += gp[(size_t)p * (TOKENS * 8192)];
      u += gp[(size_t)p * (TOKENS * 8192) + 4096];
    }
    s_b[r][t] = (g / (1.f + expf(-g))) * u;
  }
  __syncthreads();
  int c = tid * 4;
  const float* wp = Wd + ((size_t)layer << 22) + (size_t)r0 * HDIM + c;
  float4 A[8], B[8];
  float4 acc[TOKENS];
#pragma unroll
  for (int t = 0; t < TOKENS; t++) acc[t] = make_float4(0.f, 0.f, 0.f, 0.f);
  load8(A, wp, 0, HDIM);
  load8(B, wp, 1, HDIM);
  fma8(acc, A, s_b, 0);
  fma8(acc, B, s_b, 1);
  float* wdp = ws + WDP_OFF + (size_t)bid * (TOKENS * HDIM);
#pragma unroll
  for (int t = 0; t < TOKENS; t++)
    *reinterpret_cast<float4*>(wdp + (size_t)t * HDIM + c) = acc[t];
}

// ---------------- K6: h_a = h_b + sum(wdp); sumsq partials (144 blocks) -------------
__global__ __launch_bounds__(256) void k_hup(float* __restrict__ ws) {
  int t = blockIdx.x >> 3, ch = blockIdx.x & 7, c0 = ch * 128;
  int tid = threadIdx.x;
  int el = tid & 127, hf = tid >> 7;
  __shared__ float red[2][128];
  __shared__ float pr[2];
  float s = 0.f;
  const float* wp = ws + WDP_OFF + (size_t)t * HDIM + c0 + el;
#pragma unroll 8
  for (int p = hf * 128; p < hf * 128 + 128; p++) s += wp[(size_t)p * (TOKENS * HDIM)];
  red[hf][el] = s;
  __syncthreads();
  float hn = 0.f;
  if (tid < 128) {
    hn = ws[HB_OFF + (size_t)t * HDIM + c0 + tid] + red[0][tid] + red[1][tid];
    ws[HA_OFF + (size_t)t * HDIM + c0 + tid] = hn;
    float sq = hn * hn;
#pragma unroll
    for (int off = 32; off >= 1; off >>= 1) sq += __shfl_down(sq, off);
    if ((tid & 63) == 0) pr[tid >> 6] = sq;
  }
  __syncthreads();
  if (tid == 0) ws[SQP_OFF + (size_t)t * 8 + ch] = pr[0] + pr[1];
}

// ---------------- Kf1: out partials = rms(h_a[:,5:])*norm_w @ W_out -----------------
__global__ __launch_bounds__(256) void k_out(
    const float* __restrict__ Wout, const float* __restrict__ normw,
    float* __restrict__ ws) {
  const float* h = ws + HA_OFF;
  float* outp = ws + OUTP_OFF;
  __shared__ float s_rstd[8];
  __shared__ float s_b[128][8];
  int tid = threadIdx.x;
  if (tid < 8) {
    int tix = (tid >> 2) * QLEN + 5 + (tid & 3);
    float s = 0.f;
#pragma unroll
    for (int ch = 0; ch < 8; ch++) s += ws[SQP_OFF + (size_t)tix * 8 + ch];
    s_rstd[tid] = rsqrtf(s * (1.f / HDIM) + 1e-6f);
  }
  __syncthreads();
  int r0 = blockIdx.x * 128;
  for (int i = tid; i < 128 * 8; i += 256) {
    int r = i >> 3, s = i & 7;
    int tix = (s >> 2) * QLEN + 5 + (s & 3);
    s_b[r][s] = h[(size_t)tix * HDIM + r0 + r] * normw[r0 + r] * s_rstd[s];
  }
  __syncthreads();
  int colc = tid & 63, rsub = tid >> 6;
  const float* wp = Wout + (size_t)(r0 + rsub * 32) * 64 + colc;
  float acc[8];
#pragma unroll
  for (int s = 0; s < 8; s++) acc[s] = 0.f;
#pragma unroll 8
  for (int r = 0; r < 32; r++) {
    float w = wp[(size_t)r * 64];
#pragma unroll
    for (int s = 0; s < 8; s++) acc[s] += s_b[rsub * 32 + r][s] * w;
  }
  float* slot = outp + (size_t)(blockIdx.x * 4 + rsub) * 512;
#pragma unroll
  for (int s = 0; s < 8; s++) slot[s * 64 + colc] = acc[s];
}

// ---------------- Kf2: cfg combine + write d_out (float32) --------------------------
__global__ __launch_bounds__(256) void k_final(
    const float* __restrict__ rnd, const float* __restrict__ cfg,
    const float* __restrict__ cfgm, const float* __restrict__ dt_all,
    const float* __restrict__ bout, const int* __restrict__ step,
    const float* __restrict__ ws, float* __restrict__ out) {
  const float* outp = ws + OUTP_OFF;
  int tid = threadIdx.x;
  int f = tid & 63;
  float p = bout[f], n = bout[f];
#pragma unroll 8
  for (int pp = 0; pp < 32; pp++) {
    p += outp[(size_t)pp * 512 + tid];
    n += outp[(size_t)pp * 512 + 256 + tid];
  }
  float pn = p * n, nn = n * n;
#pragma unroll
  for (int off = 32; off >= 1; off >>= 1) {
    pn += __shfl_down(pn, off);
    nn += __shfl_down(nn, off);
  }
  __shared__ float red[8];
  __shared__ float s_st;
  int wave = tid >> 6, lane = tid & 63;
  if (lane == 0) { red[wave] = pn; red[4 + wave] = nn; }
  __syncthreads();
  if (tid == 0) {
    float PN = red[0] + red[1] + red[2] + red[3];
    float NN = red[4] + red[5] + red[6] + red[7];
    s_st = PN / (NN + 1e-7f);
  }
  __syncthreads();
  int st = step[0];
  float dphi = cfgm[0] * n * s_st + cfg[0] * p;
  float next = rnd[tid] - dt_all[st] * dphi;
  if (tid == 0) out[0] = (float)(st + 1);
  out[1 + tid] = next;
}

// ---------------- launch ------------------------------------------------------------
extern "C" void kernel_launch(void* const* d_in, const int* in_sizes, int n_in,
                              void* d_out, int out_size, void* d_ws, size_t ws_size,
                              hipStream_t stream) {
  const float* rnd   = (const float*)d_in[0];
  const float* dit   = (const float*)d_in[1];
  const float* feat  = (const float*)d_in[2];
  const float* cfg   = (const float*)d_in[3];
  const float* cfgm  = (const float*)d_in[4];
  const float* t_all = (const float*)d_in[5];
  const float* dt_al = (const float*)d_in[6];
  const float* cosq  = (const float*)d_in[7];
  const float* sinq  = (const float*)d_in[8];
  const float* W_in  = (const float*)d_in[9];
  const float* b_in  = (const float*)d_in[10];
  const float* ln1   = (const float*)d_in[11];
  const float* Wq    = (const float*)d_in[12];
  const float* Wk    = (const float*)d_in[13];
  const float* Wv    = (const float*)d_in[14];
  const float* Wo    = (const float*)d_in[15];
  const float* ln2   = (const float*)d_in[16];
  const float* Wg    = (const float*)d_in[17];
  const float* Wu    = (const float*)d_in[18];
  const float* Wd    = (const float*)d_in[19];
  const float* normw = (const float*)d_in[20];
  const float* Wout  = (const float*)d_in[21];
  const float* bout  = (const float*)d_in[22];
  const int*   step  = (const int*)d_in[23];
  float* ws = (float*)d_ws;

  // zero the per-layer flag counters (graph-captured; re-runs each replay)
  hipMemsetAsync((void*)(ws + CNT_OFF), 0, 64 * sizeof(unsigned), stream);

  k_embed<<<144, 256, 0, stream>>>(rnd, dit, feat, t_all, W_in, b_in, step, ws);
  for (int l = 0; l < NLAYER; l++) {
    k_qkv<<<dim3(3, 32), 256, 0, stream>>>(Wq, Wk, Wv, ln1, ws, l);
    k_redq<<<90, 256, 0, stream>>>(ws);
    k_wo<<<dim3(2, 32), 256, 0, stream>>>(Wo, cosq, sinq, ws, l);
    k_gu<<<dim3(8, 64), 256, 0, stream>>>(Wg, Wu, ln2, ws, l);
    k_wd<<<256, 256, 0, stream>>>(Wd, ws, l);
    k_hup<<<144, 256, 0, stream>>>(ws);
  }
  k_out<<<8, 256, 0, stream>>>(Wout, normw, ws);
  k_final<<<1, 256, 0, stream>>>(rnd, cfg, cfgm, dt_al, bout, step, ws, (float*)d_out);
}

// Round 8
// 549.925 us; speedup vs baseline: 1.5286x; 1.5286x over previous
//
#include <hip/hip_runtime.h>

#define TOKENS 18
#define QLEN 9
#define HDIM 1024
#define IDIM 4096
#define NLAYER 8

// ws layout (float offsets)
#define HA_OFF    0u          // h (layer input / final): [18][1024]
#define HB_OFF    18432u      // h1 after attn residual:  [18][1024]
#define SQA_OFF   36864u      // sumsq partials for HA: [18][4]
#define SQB_OFF   36936u      // sumsq partials for HB: [18][4]
#define QKVR_OFF  37008u      // reduced qkv [18][1280]
#define QKVP_OFF  60048u      // qkv partials [32][18][1280]
#define OPP_OFF   797328u     // attn-out partials [32][18][1024]
#define GUP_OFF   1387152u    // gu partials [16][18][8192]
#define M_OFF     3746448u    // m = silu(g)*u : [18][4096]
#define WDP_OFF   3820176u    // wd partials [64][18][1024]
#define OUTP_OFF  4999824u    // out partials [32][512]
#define TOTAL_F   5016208u    // ~20 MB

// ---------------- reg-dbuf GEMV helpers (proven round 6/7) --------------------------
__device__ __forceinline__ void loadf2(float2* buf, const float* wp, int base, int stride) {
#pragma unroll
  for (int j = 0; j < 8; j++)
    buf[j] = *reinterpret_cast<const float2*>(wp + (size_t)(base + j) * stride);
}
__device__ __forceinline__ void fmaf2(float2* acc, const float2* buf,
                                      const float (*sb)[TOKENS], int base) {
#pragma unroll
  for (int j = 0; j < 8; j++) {
#pragma unroll
    for (int t = 0; t < TOKENS; t++) {
      float bv = sb[base + j][t];
      acc[t].x += bv * buf[j].x; acc[t].y += bv * buf[j].y;
    }
  }
}
__device__ __forceinline__ void loadf1(float* buf, const float* wp, int base, int stride) {
#pragma unroll
  for (int j = 0; j < 8; j++) buf[j] = wp[(size_t)(base + j) * stride];
}
__device__ __forceinline__ void fmaf1(float* acc, const float* buf,
                                      const float (*sb)[TOKENS], int base) {
#pragma unroll
  for (int j = 0; j < 8; j++) {
#pragma unroll
    for (int t = 0; t < TOKENS; t++) acc[t] += sb[base + j][t] * buf[j];
  }
}

// ---------------- K0: build HA + SQA (72 blocks = 18 tok x 4 chunks of 256) ---------
__global__ __launch_bounds__(256) void k_embed(
    const float* __restrict__ rnd, const float* __restrict__ dit,
    const float* __restrict__ feat, const float* __restrict__ t_all,
    const float* __restrict__ W_in, const float* __restrict__ b_in,
    const int* __restrict__ step, float* __restrict__ ws) {
  int t = blockIdx.x >> 2, q4 = blockIdx.x & 3, c0 = q4 * 256;
  int b = t / QLEN, q = t - b * QLEN;
  int tid = threadIdx.x, c = c0 + tid;
  int st = step[0];
  __shared__ float rl[64];
  __shared__ float pr[4];
  float v;
  if (q == 0) {
    v = t_all[(size_t)st * HDIM + c] + (b == 0 ? dit[c] : 0.f);
  } else if (q <= 4) {
    v = feat[(size_t)(b * 4 + q - 1) * HDIM + c];
  } else {
    int p = q - 5;
    if (tid < 64) rl[tid] = rnd[p * 64 + tid];
    __syncthreads();
    float a = b_in[c];
#pragma unroll 8
    for (int f = 0; f < 64; f++) a += rl[f] * W_in[(size_t)f * HDIM + c];
    v = a;
  }
  ws[HA_OFF + (size_t)t * HDIM + c] = v;
  float sq = v * v;
#pragma unroll
  for (int off = 32; off >= 1; off >>= 1) sq += __shfl_down(sq, off);
  if ((tid & 63) == 0) pr[tid >> 6] = sq;
  __syncthreads();
  if (tid == 0) ws[SQA_OFF + (size_t)t * 4 + q4] = pr[0] + pr[1] + pr[2] + pr[3];
}

// ---------------- K1: qkv partials = rms(HA)*ln1 @ [Wq|Wk|Wv] (3,32) ----------------
__global__ __launch_bounds__(256) void k_qkv(
    const float* __restrict__ Wq, const float* __restrict__ Wk,
    const float* __restrict__ Wv, const float* __restrict__ ln1,
    float* __restrict__ ws, int layer) {
  int ks = blockIdx.y, r0 = ks * 32, bx = blockIdx.x, tid = threadIdx.x;
  __shared__ float s_b[32][TOKENS];
  __shared__ float s_rstd[TOKENS];
  if (tid < TOKENS) {
    float s = ws[SQA_OFF + tid * 4] + ws[SQA_OFF + tid * 4 + 1]
            + ws[SQA_OFF + tid * 4 + 2] + ws[SQA_OFF + tid * 4 + 3];
    s_rstd[tid] = rsqrtf(s * (1.f / HDIM) + 1e-6f);
  }
  const float* lw = ln1 + (size_t)layer * HDIM;
  for (int i = tid; i < 576; i += 256) {
    int t = i >> 5, r = i & 31;
    s_b[r][t] = ws[HA_OFF + (size_t)t * HDIM + r0 + r] * lw[r0 + r];
  }
  __syncthreads();
  float* qp = ws + QKVP_OFF + (size_t)ks * (TOKENS * 1280);
  if (bx < 2) {
    int col = bx * 512 + tid * 2;
    const float* wp = Wq + ((size_t)layer << 20) + (size_t)r0 * HDIM + col;
    float2 A[8], B[8];
    float2 acc[TOKENS];
#pragma unroll
    for (int t = 0; t < TOKENS; t++) acc[t] = make_float2(0.f, 0.f);
    loadf2(A, wp, 0, HDIM); loadf2(B, wp, 8, HDIM);
    fmaf2(acc, A, s_b, 0);  loadf2(A, wp, 16, HDIM);
    fmaf2(acc, B, s_b, 8);  loadf2(B, wp, 24, HDIM);
    fmaf2(acc, A, s_b, 16); fmaf2(acc, B, s_b, 24);
#pragma unroll
    for (int t = 0; t < TOKENS; t++) {
      float rs = s_rstd[t];
      *reinterpret_cast<float2*>(qp + (size_t)t * 1280 + col) = make_float2(acc[t].x * rs, acc[t].y * rs);
    }
  } else {
    int c = tid;   // 0..127 -> K cols, 128..255 -> V cols
    const float* wp = (c < 128)
      ? (Wk + (size_t)layer * 131072 + (size_t)r0 * 128 + c)
      : (Wv + (size_t)layer * 131072 + (size_t)r0 * 128 + (c - 128));
    float A[8], B[8];
    float acc[TOKENS];
#pragma unroll
    for (int t = 0; t < TOKENS; t++) acc[t] = 0.f;
    loadf1(A, wp, 0, 128); loadf1(B, wp, 8, 128);
    fmaf1(acc, A, s_b, 0);  loadf1(A, wp, 16, 128);
    fmaf1(acc, B, s_b, 8);  loadf1(B, wp, 24, 128);
    fmaf1(acc, A, s_b, 16); fmaf1(acc, B, s_b, 24);
#pragma unroll
    for (int t = 0; t < TOKENS; t++) qp[(size_t)t * 1280 + 1024 + c] = acc[t] * s_rstd[t];
  }
}

// ---------------- K2: reduce qkv partials (90 blocks, 32 slabs) ---------------------
__global__ __launch_bounds__(256) void k_redq(float* __restrict__ ws) {
  int el = blockIdx.x * 256 + threadIdx.x;   // 23040 exactly
  float s = 0.f;
#pragma unroll 8
  for (int p = 0; p < 32; p++) s += ws[QKVP_OFF + (size_t)p * (TOKENS * 1280) + el];
  ws[QKVR_OFF + el] = s;
}

// ---------------- K3: attn (from QKVR) + Wo partials (2,32) -------------------------
__global__ __launch_bounds__(256) void k_wo(
    const float* __restrict__ Wo, const float* __restrict__ cosq,
    const float* __restrict__ sinq, float* __restrict__ ws, int layer) {
  const float* qkv = ws + QKVR_OFF;
  int bx = blockIdx.x, by = blockIdx.y, tid = threadIdx.x;
  int r0 = by * 32, head = r0 >> 6, kvh = head >> 3, d0 = r0 & 63;
  __shared__ float lq[2][QLEN][68];
  __shared__ float lk[2][QLEN][68];
  __shared__ float lv[2][QLEN][33];
  __shared__ float sP[2][QLEN][12];
  __shared__ float sA[32][TOKENS];
  for (int i = tid; i < 2 * QLEN * 64; i += 256) {
    int d = i & 63, qi = (i >> 6) % QLEN, b = i / (QLEN * 64);
    const float* qr = qkv + (size_t)(b * QLEN + qi) * 1280;
    float c = cosq[qi * 64 + d], s = sinq[qi * 64 + d];
    float qv = qr[head * 64 + d];
    float qo = (d < 32) ? -qr[head * 64 + d + 32] : qr[head * 64 + d - 32];
    lq[b][qi][d] = qv * c + qo * s;
    float kv = qr[1024 + kvh * 64 + d];
    float ko = (d < 32) ? -qr[1024 + kvh * 64 + d + 32] : qr[1024 + kvh * 64 + d - 32];
    lk[b][qi][d] = kv * c + ko * s;
  }
  for (int i = tid; i < 2 * QLEN * 32; i += 256) {
    int d = i & 31, ki = (i >> 5) % QLEN, b = i / (QLEN * 32);
    lv[b][ki][d] = qkv[(size_t)(b * QLEN + ki) * 1280 + 1152 + kvh * 64 + d0 + d];
  }
  __syncthreads();
  for (int i = tid; i < 2 * QLEN * QLEN; i += 256) {
    int ki = i % QLEN, qi = (i / QLEN) % QLEN, b = i / (QLEN * QLEN);
    float s = 0.f;
#pragma unroll
    for (int d = 0; d < 64; d++) s += lq[b][qi][d] * lk[b][ki][d];
    sP[b][qi][ki] = s;
  }
  __syncthreads();
  if (tid < TOKENS) {
    int b = tid / QLEN, qi = tid % QLEN;
    float m = -1e30f;
#pragma unroll
    for (int k = 0; k < QLEN; k++) m = fmaxf(m, sP[b][qi][k]);
    float e[QLEN], sum = 0.f;
#pragma unroll
    for (int k = 0; k < QLEN; k++) { e[k] = expf(sP[b][qi][k] - m); sum += e[k]; }
    float inv = 1.f / sum;
#pragma unroll
    for (int k = 0; k < QLEN; k++) sP[b][qi][k] = e[k] * inv;
  }
  __syncthreads();
  for (int i = tid; i < 32 * TOKENS; i += 256) {
    int dd = i / TOKENS, t = i - dd * TOKENS;
    int b = t / QLEN, qi = t % QLEN;
    float a = 0.f;
#pragma unroll
    for (int k = 0; k < QLEN; k++) a += sP[b][qi][k] * lv[b][k][dd];
    sA[dd][t] = a;
  }
  __syncthreads();
  int col = bx * 512 + tid * 2;
  const float* wp = Wo + ((size_t)layer << 20) + (size_t)r0 * HDIM + col;
  float2 A[8], B[8];
  float2 acc[TOKENS];
#pragma unroll
  for (int t = 0; t < TOKENS; t++) acc[t] = make_float2(0.f, 0.f);
  loadf2(A, wp, 0, HDIM); loadf2(B, wp, 8, HDIM);
  fmaf2(acc, A, sA, 0);   loadf2(A, wp, 16, HDIM);
  fmaf2(acc, B, sA, 8);   loadf2(B, wp, 24, HDIM);
  fmaf2(acc, A, sA, 16);  fmaf2(acc, B, sA, 24);
  float* op = ws + OPP_OFF + (size_t)by * (TOKENS * HDIM);
#pragma unroll
  for (int t = 0; t < TOKENS; t++)
    *reinterpret_cast<float2*>(op + (size_t)t * HDIM + col) = acc[t];
}

// ---------------- K4: HB = HA + sum(opp); SQB (72 blocks) ---------------------------
__global__ __launch_bounds__(256) void k_redo(float* __restrict__ ws) {
  int t = blockIdx.x >> 2, q4 = blockIdx.x & 3;
  int tid = threadIdx.x, c = q4 * 256 + tid;
  __shared__ float pr[4];
  float v = ws[HA_OFF + (size_t)t * HDIM + c];
  const float* pp = ws + OPP_OFF + (size_t)t * HDIM + c;
#pragma unroll 8
  for (int p = 0; p < 32; p++) v += pp[(size_t)p * (TOKENS * HDIM)];
  ws[HB_OFF + (size_t)t * HDIM + c] = v;
  float sq = v * v;
#pragma unroll
  for (int off = 32; off >= 1; off >>= 1) sq += __shfl_down(sq, off);
  if ((tid & 63) == 0) pr[tid >> 6] = sq;
  __syncthreads();
  if (tid == 0) ws[SQB_OFF + (size_t)t * 4 + q4] = pr[0] + pr[1] + pr[2] + pr[3];
}

// ---------------- K5: gu partials = rms(HB)*ln2 @ [Wg|Wu] (32,16), 64-deep ----------
__global__ __launch_bounds__(256) void k_gu(
    const float* __restrict__ Wg, const float* __restrict__ Wu,
    const float* __restrict__ ln2, float* __restrict__ ws, int layer) {
  int cs = blockIdx.x, ks = blockIdx.y, r0 = ks * 64, tid = threadIdx.x;
  __shared__ float s_b[TOKENS][64];
  __shared__ float s_rstd[TOKENS];
  if (tid < TOKENS) {
    float s = ws[SQB_OFF + tid * 4] + ws[SQB_OFF + tid * 4 + 1]
            + ws[SQB_OFF + tid * 4 + 2] + ws[SQB_OFF + tid * 4 + 3];
    s_rstd[tid] = rsqrtf(s * (1.f / HDIM) + 1e-6f);
  }
  const float* lw = ln2 + (size_t)layer * HDIM;
  for (int i = tid; i < TOKENS * 64; i += 256) {
    int t = i >> 6, r = i & 63;
    s_b[t][r] = ws[HB_OFF + (size_t)t * HDIM + r0 + r] * lw[r0 + r];
  }
  __syncthreads();
  const float* W = (cs < 16 ? Wg : Wu) + ((size_t)layer << 22);
  int base = (cs & 15) * 256;
  const float* wp = W + (size_t)r0 * IDIM + base + tid;
  float wbuf[64];
#pragma unroll
  for (int j = 0; j < 64; j++) wbuf[j] = wp[(size_t)j * IDIM];
  float acc[TOKENS];
#pragma unroll
  for (int t = 0; t < TOKENS; t++) acc[t] = 0.f;
#pragma unroll
  for (int j = 0; j < 64; j++) {
#pragma unroll
    for (int t = 0; t < TOKENS; t++) acc[t] += s_b[t][j] * wbuf[j];
  }
  int outcol = (cs < 16 ? base : 4096 + base) + tid;
  float* gp = ws + GUP_OFF + (size_t)ks * (TOKENS * 8192) + outcol;
#pragma unroll
  for (int t = 0; t < TOKENS; t++) gp[(size_t)t * 8192] = acc[t] * s_rstd[t];
}

// ---------------- K6: m = silu(sum g)*sum u (288 blocks, exact-once reads) ----------
__global__ __launch_bounds__(256) void k_m(float* __restrict__ ws) {
  int el = blockIdx.x * 256 + threadIdx.x;   // 73728 = 18*4096
  int t = el >> 12, j = el & 4095;
  const float* gp = ws + GUP_OFF + (size_t)t * 8192 + j;
  float g = 0.f, u = 0.f;
#pragma unroll 8
  for (int p = 0; p < 16; p++) {
    g += gp[(size_t)p * (TOKENS * 8192)];
    u += gp[(size_t)p * (TOKENS * 8192) + 4096];
  }
  ws[M_OFF + (size_t)t * 4096 + j] = (g / (1.f + expf(-g))) * u;
}

// ---------------- K7: wd partials = m @ Wd (256 blocks, 64-deep, 64 slabs) ----------
__global__ __launch_bounds__(256) void k_wd(
    const float* __restrict__ Wd, float* __restrict__ ws, int layer) {
  int ks2 = blockIdx.x >> 3, cs = blockIdx.x & 7;
  int r0 = ks2 * 128, c0 = cs * 128;
  int tid = threadIdx.x, colt = tid & 127, hf = tid >> 7;
  __shared__ float s_b[TOKENS][128];
  for (int i = tid; i < TOKENS * 128; i += 256) {
    int t = i >> 7, r = i & 127;
    s_b[t][r] = ws[M_OFF + (size_t)t * 4096 + r0 + r];
  }
  __syncthreads();
  int col = c0 + colt;
  const float* wp = Wd + ((size_t)layer << 22) + (size_t)(r0 + hf * 64) * HDIM + col;
  float wbuf[64];
#pragma unroll
  for (int j = 0; j < 64; j++) wbuf[j] = wp[(size_t)j * HDIM];
  float acc[TOKENS];
#pragma unroll
  for (int t = 0; t < TOKENS; t++) acc[t] = 0.f;
#pragma unroll
  for (int j = 0; j < 64; j++) {
#pragma unroll
    for (int t = 0; t < TOKENS; t++) acc[t] += s_b[t][hf * 64 + j] * wbuf[j];
  }
  int slab = ks2 * 2 + hf;
  float* wdp = ws + WDP_OFF + (size_t)slab * (TOKENS * HDIM) + col;
#pragma unroll
  for (int t = 0; t < TOKENS; t++) wdp[(size_t)t * HDIM] = acc[t];
}

// ---------------- K8: HA = HB + sum(wdp); SQA (72 blocks) ---------------------------
__global__ __launch_bounds__(256) void k_hup(float* __restrict__ ws) {
  int t = blockIdx.x >> 2, q4 = blockIdx.x & 3;
  int tid = threadIdx.x, c = q4 * 256 + tid;
  __shared__ float pr[4];
  float v = ws[HB_OFF + (size_t)t * HDIM + c];
  const float* pp = ws + WDP_OFF + (size_t)t * HDIM + c;
#pragma unroll 8
  for (int p = 0; p < 64; p++) v += pp[(size_t)p * (TOKENS * HDIM)];
  ws[HA_OFF + (size_t)t * HDIM + c] = v;
  float sq = v * v;
#pragma unroll
  for (int off = 32; off >= 1; off >>= 1) sq += __shfl_down(sq, off);
  if ((tid & 63) == 0) pr[tid >> 6] = sq;
  __syncthreads();
  if (tid == 0) ws[SQA_OFF + (size_t)t * 4 + q4] = pr[0] + pr[1] + pr[2] + pr[3];
}

// ---------------- Kf1: out partials = rms(HA[:,5:])*norm_w @ W_out ------------------
__global__ __launch_bounds__(256) void k_out(
    const float* __restrict__ Wout, const float* __restrict__ normw,
    float* __restrict__ ws) {
  const float* h = ws + HA_OFF;
  float* outp = ws + OUTP_OFF;
  __shared__ float s_rstd[8];
  __shared__ float s_b[128][8];
  int tid = threadIdx.x;
  if (tid < 8) {
    int tix = (tid >> 2) * QLEN + 5 + (tid & 3);
    float s = ws[SQA_OFF + tix * 4] + ws[SQA_OFF + tix * 4 + 1]
            + ws[SQA_OFF + tix * 4 + 2] + ws[SQA_OFF + tix * 4 + 3];
    s_rstd[tid] = rsqrtf(s * (1.f / HDIM) + 1e-6f);
  }
  __syncthreads();
  int r0 = blockIdx.x * 128;
  for (int i = tid; i < 128 * 8; i += 256) {
    int r = i >> 3, s = i & 7;
    int tix = (s >> 2) * QLEN + 5 + (s & 3);
    s_b[r][s] = h[(size_t)tix * HDIM + r0 + r] * normw[r0 + r] * s_rstd[s];
  }
  __syncthreads();
  int colc = tid & 63, rsub = tid >> 6;
  const float* wp = Wout + (size_t)(r0 + rsub * 32) * 64 + colc;
  float acc[8];
#pragma unroll
  for (int s = 0; s < 8; s++) acc[s] = 0.f;
#pragma unroll 8
  for (int r = 0; r < 32; r++) {
    float w = wp[(size_t)r * 64];
#pragma unroll
    for (int s = 0; s < 8; s++) acc[s] += s_b[rsub * 32 + r][s] * w;
  }
  float* slot = outp + (size_t)(blockIdx.x * 4 + rsub) * 512;
#pragma unroll
  for (int s = 0; s < 8; s++) slot[s * 64 + colc] = acc[s];
}

// ---------------- Kf2: cfg combine + write d_out (float32) --------------------------
__global__ __launch_bounds__(256) void k_final(
    const float* __restrict__ rnd, const float* __restrict__ cfg,
    const float* __restrict__ cfgm, const float* __restrict__ dt_all,
    const float* __restrict__ bout, const int* __restrict__ step,
    const float* __restrict__ ws, float* __restrict__ out) {
  const float* outp = ws + OUTP_OFF;
  int tid = threadIdx.x;
  int f = tid & 63;
  float p = bout[f], n = bout[f];
#pragma unroll 8
  for (int pp = 0; pp < 32; pp++) {
    p += outp[(size_t)pp * 512 + tid];
    n += outp[(size_t)pp * 512 + 256 + tid];
  }
  float pn = p * n, nn = n * n;
#pragma unroll
  for (int off = 32; off >= 1; off >>= 1) {
    pn += __shfl_down(pn, off);
    nn += __shfl_down(nn, off);
  }
  __shared__ float red[8];
  __shared__ float s_st;
  int wave = tid >> 6, lane = tid & 63;
  if (lane == 0) { red[wave] = pn; red[4 + wave] = nn; }
  __syncthreads();
  if (tid == 0) {
    float PN = red[0] + red[1] + red[2] + red[3];
    float NN = red[4] + red[5] + red[6] + red[7];
    s_st = PN / (NN + 1e-7f);
  }
  __syncthreads();
  int st = step[0];
  float dphi = cfgm[0] * n * s_st + cfg[0] * p;
  float next = rnd[tid] - dt_all[st] * dphi;
  if (tid == 0) out[0] = (float)(st + 1);
  out[1 + tid] = next;
}

// ---------------- launch ------------------------------------------------------------
extern "C" void kernel_launch(void* const* d_in, const int* in_sizes, int n_in,
                              void* d_out, int out_size, void* d_ws, size_t ws_size,
                              hipStream_t stream) {
  const float* rnd   = (const float*)d_in[0];
  const float* dit   = (const float*)d_in[1];
  const float* feat  = (const float*)d_in[2];
  const float* cfg   = (const float*)d_in[3];
  const float* cfgm  = (const float*)d_in[4];
  const float* t_all = (const float*)d_in[5];
  const float* dt_al = (const float*)d_in[6];
  const float* cosq  = (const float*)d_in[7];
  const float* sinq  = (const float*)d_in[8];
  const float* W_in  = (const float*)d_in[9];
  const float* b_in  = (const float*)d_in[10];
  const float* ln1   = (const float*)d_in[11];
  const float* Wq    = (const float*)d_in[12];
  const float* Wk    = (const float*)d_in[13];
  const float* Wv    = (const float*)d_in[14];
  const float* Wo    = (const float*)d_in[15];
  const float* ln2   = (const float*)d_in[16];
  const float* Wg    = (const float*)d_in[17];
  const float* Wu    = (const float*)d_in[18];
  const float* Wd    = (const float*)d_in[19];
  const float* normw = (const float*)d_in[20];
  const float* Wout  = (const float*)d_in[21];
  const float* bout  = (const float*)d_in[22];
  const int*   step  = (const int*)d_in[23];
  float* ws = (float*)d_ws;

  k_embed<<<72, 256, 0, stream>>>(rnd, dit, feat, t_all, W_in, b_in, step, ws);
  for (int l = 0; l < NLAYER; l++) {
    k_qkv<<<dim3(3, 32), 256, 0, stream>>>(Wq, Wk, Wv, ln1, ws, l);
    k_redq<<<90, 256, 0, stream>>>(ws);
    k_wo<<<dim3(2, 32), 256, 0, stream>>>(Wo, cosq, sinq, ws, l);
    k_redo<<<72, 256, 0, stream>>>(ws);
    k_gu<<<dim3(32, 16), 256, 0, stream>>>(Wg, Wu, ln2, ws, l);
    k_m<<<288, 256, 0, stream>>>(ws);
    k_wd<<<256, 256, 0, stream>>>(Wd, ws, l);
    k_hup<<<72, 256, 0, stream>>>(ws);
  }
  k_out<<<8, 256, 0, stream>>>(Wout, normw, ws);
  k_final<<<1, 256, 0, stream>>>(rnd, cfg, cfgm, dt_al, bout, step, ws, (float*)d_out);
}